// Round 9
// baseline (67.229 us; speedup 1.0000x reference)
//
#include <hip/hip_runtime.h>
#include <hip/hip_bf16.h>
#include <cstdint>

using u16 = unsigned short;
using u32 = unsigned int;

#define DEPTH 10
#define NF 512
#define NL 1024
#define BATCH_N 32768
#define TEMP_INV 10.0f
#define GBM 128
#define GBN 256
#define GBK 64
#define NSTEP (NL / GBK)   // 16

typedef float f32x4 __attribute__((ext_vector_type(4)));
typedef short s16x8 __attribute__((ext_vector_type(8)));
typedef __bf16 bf16x8 __attribute__((ext_vector_type(8)));

__device__ __forceinline__ u16 f2bf(float f) {
  u32 u = __float_as_uint(f);
  u = (u + 0x7fffu + ((u >> 16) & 1u)) >> 16;
  return (u16)u;
}

__device__ __forceinline__ void gld_lds16(const void* g, void* lds) {
  __builtin_amdgcn_global_load_lds(
      (const __attribute__((address_space(1))) void*)g,
      (__attribute__((address_space(3))) void*)lds, 16, 0, 0);
}

// ---------------- kernel 1: leaf_values f32 (512x1024) -> bf16 (same layout)
__global__ void k_cvt(const float* __restrict__ lv, u16* __restrict__ lvb) {
  int i = (blockIdx.x * blockDim.x + threadIdx.x) * 8;
  float4 a = *(const float4*)(lv + i);
  float4 b = *(const float4*)(lv + i + 4);
  uint4 u;
  u.x = f2bf(a.x) | ((u32)f2bf(a.y) << 16);
  u.y = f2bf(a.z) | ((u32)f2bf(a.w) << 16);
  u.z = f2bf(b.x) | ((u32)f2bf(b.y) << 16);
  u.w = f2bf(b.z) | ((u32)f2bf(b.w) << 16);
  *(uint4*)(lvb + i) = u;
}

// ---------------- kernel 2: softmax(fw) in-block + sel -> sigmoid -> p[32768][10]
__global__ __launch_bounds__(256, 4) void k_sel(const float* __restrict__ x,
                                                const float* __restrict__ fw,
                                                const float* __restrict__ thr,
                                                float* __restrict__ pout) {
  __shared__ float Ps[DEPTH * NF];  // 20 KB, plain [10][512]
  const int tid = threadIdx.x;
  const int lane = tid & 63;
  const int w = tid >> 6;

  for (int d = w; d < DEPTH; d += 4) {
    const float* row = fw + d * NF;
    float v[8];
    float mx = -1e30f;
#pragma unroll
    for (int i = 0; i < 8; ++i) { v[i] = row[lane * 8 + i]; mx = fmaxf(mx, v[i]); }
#pragma unroll
    for (int s = 32; s >= 1; s >>= 1) mx = fmaxf(mx, __shfl_xor(mx, s));
    float sum = 0.f;
#pragma unroll
    for (int i = 0; i < 8; ++i) { v[i] = __expf(v[i] - mx); sum += v[i]; }
#pragma unroll
    for (int s = 32; s >= 1; s >>= 1) sum += __shfl_xor(sum, s);
    float inv = 1.0f / sum;
#pragma unroll
    for (int i = 0; i < 8; ++i) Ps[d * NF + lane * 8 + i] = v[i] * inv;
  }
  __syncthreads();

  const int g = lane & 15;
  const int qr = lane >> 4;
  const int r0 = blockIdx.x * 32 + (w * 4 + qr) * 2;
  const float* xp0 = x + (size_t)r0 * NF + g * 4;
  const float* xp1 = xp0 + NF;

  float a0[DEPTH], a1[DEPTH];
#pragma unroll
  for (int d = 0; d < DEPTH; ++d) { a0[d] = 0.f; a1[d] = 0.f; }
#pragma unroll 2
  for (int i = 0; i < 8; ++i) {
    float4 xv0 = *(const float4*)(xp0 + i * 64);
    float4 xv1 = *(const float4*)(xp1 + i * 64);
    const float* pb = &Ps[i * 64 + g * 4];
#pragma unroll
    for (int d = 0; d < DEPTH; ++d) {
      f32x4 pv = *(const f32x4*)(pb + d * NF);
      a0[d] += xv0.x * pv[0] + xv0.y * pv[1] + xv0.z * pv[2] + xv0.w * pv[3];
      a1[d] += xv1.x * pv[0] + xv1.y * pv[1] + xv1.z * pv[2] + xv1.w * pv[3];
    }
  }
#pragma unroll
  for (int d = 0; d < DEPTH; ++d) {
    a0[d] += __shfl_xor(a0[d], 1); a0[d] += __shfl_xor(a0[d], 2);
    a0[d] += __shfl_xor(a0[d], 4); a0[d] += __shfl_xor(a0[d], 8);
    a1[d] += __shfl_xor(a1[d], 1); a1[d] += __shfl_xor(a1[d], 2);
    a1[d] += __shfl_xor(a1[d], 4); a1[d] += __shfl_xor(a1[d], 8);
  }
  if (g < DEPTH) {
    float s0 = (g == 0) ? a0[0] : (g == 1) ? a0[1] : (g == 2) ? a0[2]
             : (g == 3) ? a0[3] : (g == 4) ? a0[4] : (g == 5) ? a0[5]
             : (g == 6) ? a0[6] : (g == 7) ? a0[7] : (g == 8) ? a0[8] : a0[9];
    float s1 = (g == 0) ? a1[0] : (g == 1) ? a1[1] : (g == 2) ? a1[2]
             : (g == 3) ? a1[3] : (g == 4) ? a1[4] : (g == 5) ? a1[5]
             : (g == 6) ? a1[6] : (g == 7) ? a1[7] : (g == 8) ? a1[8] : a1[9];
    float t = thr[g];
    pout[(size_t)r0 * DEPTH + g]       = 1.0f / (1.0f + __expf(-(s0 - t) * TEMP_INV));
    pout[(size_t)(r0 + 1) * DEPTH + g] = 1.0f / (1.0f + __expf(-(s1 - t) * TEMP_INV));
  }
}

// ---------------- kernel 3: GEMM  C[128x256] = leafprob(reg-gen) @ lvb^T
// A fragments generated DIRECTLY in registers (no A-LDS): lane owns 4 rows,
// T-slice (8 regs/row, step-invariant) x H scalar (ratio form, 4 cndmask-mul).
// Bs only in LDS: GBK=64, 2 x 32KB double buffer, one barrier per 64-K step.
__global__ __launch_bounds__(256, 2) void k_gemm(const u16* __restrict__ B,
                                                 const float* __restrict__ p,
                                                 float* __restrict__ C) {
  __shared__ char smem[65536];  // Bs: 2 x [256 rows][128 B], slot-swizzled
  const int tid = threadIdx.x;
  const int lane = tid & 63;
  const int w = tid >> 6;       // 0..3
  const int wm = w >> 1, wn = w & 1;
  const int bm = blockIdx.x >> 1, bn = blockIdx.x & 1;
  const int brow = bm * GBM, bcol = bn * GBN;
  const int rA = lane & 15, sg = lane >> 4;

  // ---- per-lane A-generator state for its 4 rows (m=0..3) ----
  // leaf = kk*64 + kh*32 + sg*8 + j ; bit(9-d) selects p_d vs 1-p_d
  // hi = leaf>>5 = 2kk+kh: kk&8->d0, kk&4->d1, kk&2->d2, kk&1->d3, kh->d4
  // lo = sg*8+j: sg&2->d5, sg&1->d6, j&4->d7, j&2->d8, j&1->d9
  float T[4][8];
  float base0[4], r0_[4], r1_[4], r2_[4], r3_[4], r4_[4];
#pragma unroll
  for (int m = 0; m < 4; ++m) {
    const float* pr = p + (size_t)(brow + wm * 64 + m * 16 + rA) * DEPTH;
    float p0 = pr[0], p1 = pr[1], p2 = pr[2], p3 = pr[3], p4 = pr[4];
    float p5 = pr[5], p6 = pr[6], p7 = pr[7], p8 = pr[8], p9 = pr[9];
    float q0 = 1.f - p0, q1 = 1.f - p1, q2 = 1.f - p2, q3 = 1.f - p3, q4 = 1.f - p4;
    base0[m] = q0 * q1 * q2 * q3 * q4;        // H(hi=0)
    r0_[m] = p0 / q0; r1_[m] = p1 / q1; r2_[m] = p2 / q2;
    r3_[m] = p3 / q3; r4_[m] = p4 / q4;
    float s56 = ((sg & 2) ? p5 : 1.f - p5) * ((sg & 1) ? p6 : 1.f - p6);
    float a7 = 1.f - p7, b7 = p7, a8 = 1.f - p8, b8 = p8, a9 = 1.f - p9, b9 = p9;
#pragma unroll
    for (int j = 0; j < 8; ++j)
      T[m][j] = s56 * ((j & 4) ? b7 : a7) * ((j & 2) ? b8 : a8) * ((j & 1) ? b9 : a9);
  }

  f32x4 acc[4][8];
#pragma unroll
  for (int m = 0; m < 4; ++m)
#pragma unroll
    for (int n = 0; n < 8; ++n) acc[m][n] = {0.f, 0.f, 0.f, 0.f};

  auto STAGE = [&](int step, int buf) {
    char* bsb = smem + buf * 32768;
#pragma unroll
    for (int it = 0; it < 8; ++it) {
      int lin = it * 256 + tid;
      int r = lin >> 3;                       // B row 0..255
      int sl = (lin & 7) ^ (r & 7);           // inverse swizzle on source
      gld_lds16(B + (size_t)(bcol + r) * NL + step * GBK + sl * 8, bsb + lin * 16);
    }
  };

  STAGE(0, 0);
  asm volatile("s_waitcnt vmcnt(0)" ::: "memory");
  __builtin_amdgcn_s_barrier();

#pragma unroll 1
  for (int kk = 0; kk < NSTEP; ++kk) {
    if (kk < NSTEP - 1) STAGE(kk + 1, (kk + 1) & 1);
    const char* bb = smem + (kk & 1) * 32768;

    // H(2kk) per row: base0 * selected ratios (cndmask vs 1.0)
    float H[4];
#pragma unroll
    for (int m = 0; m < 4; ++m) {
      float g = base0[m] * ((kk & 8) ? r0_[m] : 1.0f);
      g *= (kk & 4) ? r1_[m] : 1.0f;
      g *= (kk & 2) ? r2_[m] : 1.0f;
      g *= (kk & 1) ? r3_[m] : 1.0f;
      H[m] = g;
    }
    // kh = 0 pass (A = H * T)
    {
      bf16x8 af[4];
#pragma unroll
      for (int m = 0; m < 4; ++m)
#pragma unroll
        for (int j = 0; j < 8; ++j) af[m][j] = (__bf16)(H[m] * T[m][j]);
#pragma unroll
      for (int n = 0; n < 8; ++n) {
        int row = wn * 128 + n * 16 + rA;
        bf16x8 bf = __builtin_bit_cast(bf16x8,
            *(const s16x8*)(bb + row * 128 + ((sg ^ (row & 7)) << 4)));
        acc[0][n] = __builtin_amdgcn_mfma_f32_16x16x32_bf16(af[0], bf, acc[0][n], 0, 0, 0);
        acc[1][n] = __builtin_amdgcn_mfma_f32_16x16x32_bf16(af[1], bf, acc[1][n], 0, 0, 0);
        acc[2][n] = __builtin_amdgcn_mfma_f32_16x16x32_bf16(af[2], bf, acc[2][n], 0, 0, 0);
        acc[3][n] = __builtin_amdgcn_mfma_f32_16x16x32_bf16(af[3], bf, acc[3][n], 0, 0, 0);
      }
    }
    // kh = 1 pass (A = H * r4 * T)
    {
      bf16x8 af[4];
#pragma unroll
      for (int m = 0; m < 4; ++m) {
        float h1 = H[m] * r4_[m];
#pragma unroll
        for (int j = 0; j < 8; ++j) af[m][j] = (__bf16)(h1 * T[m][j]);
      }
#pragma unroll
      for (int n = 0; n < 8; ++n) {
        int row = wn * 128 + n * 16 + rA;
        bf16x8 bf = __builtin_bit_cast(bf16x8,
            *(const s16x8*)(bb + row * 128 + (((4 + sg) ^ (row & 7)) << 4)));
        acc[0][n] = __builtin_amdgcn_mfma_f32_16x16x32_bf16(af[0], bf, acc[0][n], 0, 0, 0);
        acc[1][n] = __builtin_amdgcn_mfma_f32_16x16x32_bf16(af[1], bf, acc[1][n], 0, 0, 0);
        acc[2][n] = __builtin_amdgcn_mfma_f32_16x16x32_bf16(af[2], bf, acc[2][n], 0, 0, 0);
        acc[3][n] = __builtin_amdgcn_mfma_f32_16x16x32_bf16(af[3], bf, acc[3][n], 0, 0, 0);
      }
    }
    if (kk < NSTEP - 1) {
      asm volatile("s_waitcnt vmcnt(0) lgkmcnt(0)" ::: "memory");
      __builtin_amdgcn_s_barrier();
    }
  }

  // ---- epilogue: C/D map col=lane&15, row=(lane>>4)*4+reg ----
  const int c0 = lane & 15;
  const int rr = (lane >> 4) * 4;
#pragma unroll
  for (int m = 0; m < 4; ++m)
#pragma unroll
    for (int n = 0; n < 8; ++n) {
      int col = bcol + wn * 128 + n * 16 + c0;
#pragma unroll
      for (int r = 0; r < 4; ++r)
        C[(size_t)(brow + wm * 64 + m * 16 + rr + r) * NF + col] = acc[m][n][r];
    }
}

extern "C" void kernel_launch(void* const* d_in, const int* in_sizes, int n_in,
                              void* d_out, int out_size, void* d_ws, size_t ws_size,
                              hipStream_t stream) {
  const float* x  = (const float*)d_in[0];
  const float* fw = (const float*)d_in[1];
  const float* th = (const float*)d_in[2];
  const float* lv = (const float*)d_in[3];
  float* out = (float*)d_out;

  u16* lvb = (u16*)d_ws;                                  // 1 MB
  float* pbuf = (float*)((char*)d_ws + NF * NL * 2);      // 1.3 MB

  k_cvt<<<(NF * NL / 8) / 256, 256, 0, stream>>>(lv, lvb);
  k_sel<<<BATCH_N / 32, 256, 0, stream>>>(x, fw, th, pbuf);
  k_gemm<<<(BATCH_N / GBM) * 2, 256, 0, stream>>>(lvb, pbuf, out);
}